// Round 1
// baseline (243.275 us; speedup 1.0000x reference)
//
#include <hip/hip_runtime.h>

// IF neuron, multi-step, hard reset:
//   h_t = x_t + v_{t-1};  s_t = (h_t >= 1.0);  v_t = s_t ? 0 : h_t
//
// R7 theory: stores in the main loop share the vmcnt FIFO with the
// prefetch loads (vmcnt retires in issue order), so every load-wait is
// really a wait on a 3-iteration-old NT store ack (~us under 2.5 TB/s
// write traffic). Evidence: deepening the load prefetch (R4->R6) did NOT
// help; fillBuffer streams 6.7 TB/s on the same buffers.
//
// Fix: two-phase kernel.
//   Phase 1: pure-load pipeline (depth-4 rotating float4 prefetch), spikes
//            packed into 128 bits of registers (4 bits/t * 32 t).
//   Phase 2: expand bits -> 0.0/1.0 floats, NT-stream all stores
//            (fillBuffer regime). BW cost of the split is zero:
//            reads(22us) + writes(20us) ~= overlapped roofline 43us.

typedef float v4f __attribute__((ext_vector_type(4)));
typedef float v2f __attribute__((ext_vector_type(2)));

template <int T, int D>   // D = prefetch depth (iterations ahead)
__global__ __launch_bounds__(256) void if_node_f4_bits(
    const float* __restrict__ x,    // (T, N)
    const float* __restrict__ v0,   // (N,)
    float* __restrict__ out,        // (T, N)
    long n4)                        // N/4
{
    long i = (long)blockIdx.x * blockDim.x + threadIdx.x;
    if (i >= n4) return;

    const v4f* __restrict__ x4 = (const v4f*)x;
    v4f*       __restrict__ o4 = (v4f*)out;

    v4f v = ((const v4f*)v0)[i];

    constexpr int S = D + 1;        // rotating slots
    v4f buf[S];

    // Prologue: fill the pipe with t = 0..D-1.
#pragma unroll
    for (int t = 0; t < D; ++t)
        buf[t % S] = x4[(long)t * n4 + i];
    __builtin_amdgcn_sched_barrier(0);

    static_assert(T % 8 == 0, "bit-pack assumes T % 8 == 0");
    unsigned bits[T / 8];           // 4 spike bits per timestep
#pragma unroll
    for (int w = 0; w < T / 8; ++w) bits[w] = 0u;

    // Phase 1: pure-load pipeline. No stores -> vmcnt waits are exact.
#pragma unroll
    for (int t = 0; t < T; ++t) {
        if (t + D < T)
            buf[(t + D) % S] = x4[(long)(t + D) * n4 + i];
        __builtin_amdgcn_sched_barrier(0);

        v4f xv = buf[t % S];
#pragma unroll
        for (int c = 0; c < 4; ++c) {
            float h = xv[c] + v[c];
            bool s = h >= 1.0f;     // == (h - 1.0f) >= 0 for all finite h
            bits[t / 8] |= (s ? 1u : 0u) << ((t % 8) * 4 + c);
            v[c] = s ? 0.0f : h;
        }
        __builtin_amdgcn_sched_barrier(0);
    }

    // Hard fence: keep phase-2 stores out of the load pipeline.
    __builtin_amdgcn_sched_barrier(0);

    // Phase 2: expand and stream. Fire-and-forget NT stores, no waits.
#pragma unroll
    for (int t = 0; t < T; ++t) {
        v4f s;
#pragma unroll
        for (int c = 0; c < 4; ++c)
            s[c] = ((bits[t / 8] >> ((t % 8) * 4 + c)) & 1u) ? 1.0f : 0.0f;
        __builtin_nontemporal_store(s, &o4[(long)t * n4 + i]);
    }
}

// Fallbacks for shapes the fast path doesn't cover.
__global__ __launch_bounds__(256) void if_node_f2_generic(
    const float* __restrict__ x, const float* __restrict__ v0,
    float* __restrict__ out, long n2, int T)
{
    long i = (long)blockIdx.x * blockDim.x + threadIdx.x;
    if (i >= n2) return;
    const v2f* x2 = (const v2f*)x;
    v2f*       o2 = (v2f*)out;
    v2f v = ((const v2f*)v0)[i];
    for (int t = 0; t < T; ++t) {
        v2f xv = x2[(long)t * n2 + i];
        float hx = xv.x + v.x;
        float hy = xv.y + v.y;
        bool sx = hx >= 1.0f;
        bool sy = hy >= 1.0f;
        v2f s;
        s.x = sx ? 1.0f : 0.0f;
        s.y = sy ? 1.0f : 0.0f;
        v.x = sx ? 0.0f : hx;
        v.y = sy ? 0.0f : hy;
        o2[(long)t * n2 + i] = s;
    }
}

__global__ __launch_bounds__(256) void if_node_scalar(
    const float* __restrict__ x, const float* __restrict__ v0,
    float* __restrict__ out, long n, int T)
{
    long i = (long)blockIdx.x * blockDim.x + threadIdx.x;
    if (i >= n) return;
    float v = v0[i];
    for (int t = 0; t < T; ++t) {
        float h = x[(long)t * n + i] + v;
        bool s = h >= 1.0f;
        out[(long)t * n + i] = s ? 1.0f : 0.0f;
        v = s ? 0.0f : h;
    }
}

extern "C" void kernel_launch(void* const* d_in, const int* in_sizes, int n_in,
                              void* d_out, int out_size, void* d_ws, size_t ws_size,
                              hipStream_t stream) {
    const float* x  = (const float*)d_in[0];   // (T, B, D) fp32
    const float* v0 = (const float*)d_in[1];   // (B, D) fp32
    float* out = (float*)d_out;                // (T, B, D) fp32

    long n = in_sizes[1];                      // B*D
    int  T = (int)(in_sizes[0] / n);           // 32

    int block = 256;
    if (T == 32 && (n % 4) == 0) {
        long n4 = n >> 2;                      // float4 elements
        long grid = (n4 + block - 1) / block;  // 1024 blocks at N=1M
        if_node_f4_bits<32, 4><<<dim3((unsigned)grid), dim3(block), 0, stream>>>(
            x, v0, out, n4);
    } else if ((n & 1) == 0) {
        long n2 = n >> 1;
        long grid = (n2 + block - 1) / block;
        if_node_f2_generic<<<dim3((unsigned)grid), dim3(block), 0, stream>>>(
            x, v0, out, n2, T);
    } else {
        long grid = (n + block - 1) / block;
        if_node_scalar<<<dim3((unsigned)grid), dim3(block), 0, stream>>>(
            x, v0, out, n, T);
    }
}

// Round 2
// 235.840 us; speedup vs baseline: 1.0315x; 1.0315x over previous
//
#include <hip/hip_runtime.h>

// IF neuron, multi-step, hard reset:
//   h_t = x_t + v_{t-1};  s_t = (h_t >= 1.0);  v_t = s_t ? 0 : h_t
//
// R8 theory: the constant across all kernels stuck at 2.3-2.5 TB/s
// (R4 74us / R6 80us / R7 89us, structure-insensitive) was
// __builtin_nontemporal_store. NT stores bypass L2/L3 -> synchronous
// HBM-rate write drain (~9 GB/s/CU observed). The 128 MiB output fits
// in the 256 MiB Infinity Cache: plain stores complete at L3 speed and
// write back lazily. fillBufferAligned (plain stores) hits 6.7 TB/s in
// the same capture. So: simplest f4 loop, depth-2 rotating prefetch,
// PLAIN stores, no sched_barriers, no phase split.

typedef float v4f __attribute__((ext_vector_type(4)));
typedef float v2f __attribute__((ext_vector_type(2)));

template <int T, int D>   // D = prefetch depth (iterations ahead)
__global__ __launch_bounds__(256) void if_node_f4_plain(
    const float* __restrict__ x,    // (T, N)
    const float* __restrict__ v0,   // (N,)
    float* __restrict__ out,        // (T, N)
    long n4)                        // N/4
{
    long i = (long)blockIdx.x * blockDim.x + threadIdx.x;
    if (i >= n4) return;

    const v4f* __restrict__ x4 = (const v4f*)x;
    v4f*       __restrict__ o4 = (v4f*)out;

    v4f v = ((const v4f*)v0)[i];

    constexpr int S = D + 1;        // rotating slots
    v4f buf[S];

    // Prologue: fill the pipe with t = 0..D-1.
#pragma unroll
    for (int t = 0; t < D; ++t)
        buf[t % S] = x4[(long)t * n4 + i];

#pragma unroll
    for (int t = 0; t < T; ++t) {
        if (t + D < T)
            buf[(t + D) % S] = x4[(long)(t + D) * n4 + i];

        v4f xv = buf[t % S];
        v4f s;
#pragma unroll
        for (int c = 0; c < 4; ++c) {
            float h = xv[c] + v[c];
            bool sp = h >= 1.0f;    // == (h - 1.0f) >= 0 for all finite h
            s[c] = sp ? 1.0f : 0.0f;
            v[c] = sp ? 0.0f : h;
        }
        // PLAIN store: lands in L2/L3 (out fits in Infinity Cache),
        // lazy writeback off the critical path.
        o4[(long)t * n4 + i] = s;
    }
}

// Fallbacks for shapes the fast path doesn't cover.
__global__ __launch_bounds__(256) void if_node_f2_generic(
    const float* __restrict__ x, const float* __restrict__ v0,
    float* __restrict__ out, long n2, int T)
{
    long i = (long)blockIdx.x * blockDim.x + threadIdx.x;
    if (i >= n2) return;
    const v2f* x2 = (const v2f*)x;
    v2f*       o2 = (v2f*)out;
    v2f v = ((const v2f*)v0)[i];
    for (int t = 0; t < T; ++t) {
        v2f xv = x2[(long)t * n2 + i];
        float hx = xv.x + v.x;
        float hy = xv.y + v.y;
        bool sx = hx >= 1.0f;
        bool sy = hy >= 1.0f;
        v2f s;
        s.x = sx ? 1.0f : 0.0f;
        s.y = sy ? 1.0f : 0.0f;
        v.x = sx ? 0.0f : hx;
        v.y = sy ? 0.0f : hy;
        o2[(long)t * n2 + i] = s;
    }
}

__global__ __launch_bounds__(256) void if_node_scalar(
    const float* __restrict__ x, const float* __restrict__ v0,
    float* __restrict__ out, long n, int T)
{
    long i = (long)blockIdx.x * blockDim.x + threadIdx.x;
    if (i >= n) return;
    float v = v0[i];
    for (int t = 0; t < T; ++t) {
        float h = x[(long)t * n + i] + v;
        bool s = h >= 1.0f;
        out[(long)t * n + i] = s ? 1.0f : 0.0f;
        v = s ? 0.0f : h;
    }
}

extern "C" void kernel_launch(void* const* d_in, const int* in_sizes, int n_in,
                              void* d_out, int out_size, void* d_ws, size_t ws_size,
                              hipStream_t stream) {
    const float* x  = (const float*)d_in[0];   // (T, B, D) fp32
    const float* v0 = (const float*)d_in[1];   // (B, D) fp32
    float* out = (float*)d_out;                // (T, B, D) fp32

    long n = in_sizes[1];                      // B*D
    int  T = (int)(in_sizes[0] / n);           // 32

    int block = 256;
    if (T == 32 && (n % 4) == 0) {
        long n4 = n >> 2;                      // float4 elements
        long grid = (n4 + block - 1) / block;  // 1024 blocks at N=1M
        if_node_f4_plain<32, 2><<<dim3((unsigned)grid), dim3(block), 0, stream>>>(
            x, v0, out, n4);
    } else if ((n & 1) == 0) {
        long n2 = n >> 1;
        long grid = (n2 + block - 1) / block;
        if_node_f2_generic<<<dim3((unsigned)grid), dim3(block), 0, stream>>>(
            x, v0, out, n2, T);
    } else {
        long grid = (n + block - 1) / block;
        if_node_scalar<<<dim3((unsigned)grid), dim3(block), 0, stream>>>(
            x, v0, out, n, T);
    }
}